// Round 1
// baseline (63.362 us; speedup 1.0000x reference)
//
#include <hip/hip_runtime.h>

// Masked cumulative sum along dim=1.
// x: (128, 131072) fp32, mask: (128, 131072) bool (layout auto-detected: int32 vs byte)
// out = cumsum(x * mask, axis=1), fp32.
//
// Structure: reduce-then-scan.
//   detect : figure out whether mask buffer is int32 (4B/elem) or bool (1B/elem)
//   p1     : per-tile masked sums (tile = 8192 elems, 16 tiles/row, 2048 blocks)
//   p2     : per-row exclusive scan of the 16 tile sums (1 block, 128 threads)
//   p3     : re-scan each tile with its row/tile offset, write output

#define TPB 256
#define B_ROWS 128
#define S_LEN 131072
#define TILE 8192
#define TILES_PER_ROW (S_LEN / TILE)   // 16
#define ROUNDS (TILE / (TPB * 4))      // 8 float4 rounds per block

// ---------------------------------------------------------------- mask loads
__device__ __forceinline__ float4 load_mask4(const void* __restrict__ mask,
                                             bool m_i32, long i4) {
    float4 m;
    if (m_i32) {
        const int4 v = ((const int4*)mask)[i4];
        m.x = (float)v.x; m.y = (float)v.y; m.z = (float)v.z; m.w = (float)v.w;
    } else {
        unsigned int w = ((const unsigned int*)mask)[i4];
        m.x = (float)(w & 0xffu);
        m.y = (float)((w >> 8) & 0xffu);
        m.z = (float)((w >> 16) & 0xffu);
        m.w = (float)((w >> 24) & 0xffu);
    }
    return m;
}

// ------------------------------------------------------------------- detect
// If the mask buffer is int32, every 4-byte word is exactly 0 or 1.
// If it's 1-byte bool, a word packs 4 bytes in {0,1}; P(word <= 1) = 1/8,
// so 4096 random words all being <=1 is impossible in practice.
__global__ void detect_kernel(const unsigned int* __restrict__ mask,
                              int* __restrict__ flag) {
    const int t = threadIdx.x;
    bool ok = true;
    #pragma unroll
    for (int i = 0; i < 16; ++i) {
        unsigned int w = mask[t * 16 + i];
        ok = ok && (w <= 1u);
    }
    __shared__ int f;
    if (t == 0) f = 1;
    __syncthreads();
    if (!ok) f = 0;                 // benign same-value race
    __syncthreads();
    if (t == 0) *flag = f;          // 1 -> int32 mask, 0 -> byte mask
}

// ----------------------------------------------------------------- phase 1
__global__ void __launch_bounds__(TPB)
p1_tile_sums(const float* __restrict__ x, const void* __restrict__ mask,
             const int* __restrict__ flag, float* __restrict__ tileSums) {
    const bool m_i32 = (*flag != 0);
    const int tl = blockIdx.x;      // tile within row
    const int r  = blockIdx.y;      // row
    const int t  = threadIdx.x;
    const long base4 = ((long)r * S_LEN + (long)tl * TILE) >> 2;
    const float4* __restrict__ x4 = (const float4*)x;

    float s = 0.0f;
    #pragma unroll
    for (int rd = 0; rd < ROUNDS; ++rd) {
        const long i4 = base4 + (long)rd * TPB + t;
        const float4 xv = x4[i4];
        const float4 mv = load_mask4(mask, m_i32, i4);
        s += xv.x * mv.x + xv.y * mv.y + xv.z * mv.z + xv.w * mv.w;
    }
    // wave reduce (64 lanes)
    #pragma unroll
    for (int off = 32; off > 0; off >>= 1) s += __shfl_down(s, off, 64);
    __shared__ float wt[4];
    const int wid = t >> 6, lane = t & 63;
    if (lane == 0) wt[wid] = s;
    __syncthreads();
    if (t == 0) tileSums[r * TILES_PER_ROW + tl] = wt[0] + wt[1] + wt[2] + wt[3];
}

// ----------------------------------------------------------------- phase 2
__global__ void p2_scan_tiles(float* __restrict__ tileSums) {
    const int r = threadIdx.x;      // 128 threads, one row each
    float run = 0.0f;
    #pragma unroll
    for (int t = 0; t < TILES_PER_ROW; ++t) {
        const float v = tileSums[r * TILES_PER_ROW + t];
        tileSums[r * TILES_PER_ROW + t] = run;   // exclusive prefix
        run += v;
    }
}

// ----------------------------------------------------------------- phase 3
__global__ void __launch_bounds__(TPB)
p3_scan(const float* __restrict__ x, const void* __restrict__ mask,
        const int* __restrict__ flag, const float* __restrict__ tileOff,
        float* __restrict__ out) {
    const bool m_i32 = (*flag != 0);
    const int tl = blockIdx.x;
    const int r  = blockIdx.y;
    const int t  = threadIdx.x;
    const int lane = t & 63, wid = t >> 6;
    const long base4 = ((long)r * S_LEN + (long)tl * TILE) >> 2;
    const float4* __restrict__ x4 = (const float4*)x;
    float4* __restrict__ o4 = (float4*)out;

    float carry = tileOff[r * TILES_PER_ROW + tl];
    __shared__ float wt[4];

    for (int rd = 0; rd < ROUNDS; ++rd) {
        const long i4 = base4 + (long)rd * TPB + t;
        const float4 xv = x4[i4];
        const float4 mv = load_mask4(mask, m_i32, i4);
        const float v0 = xv.x * mv.x;
        const float v1 = xv.y * mv.y;
        const float v2 = xv.z * mv.z;
        const float v3 = xv.w * mv.w;
        const float p0 = v0;
        const float p1 = p0 + v1;
        const float p2 = p1 + v2;
        const float p3 = p2 + v3;
        const float s  = p3;          // thread-local sum of 4

        // wave-inclusive scan of s
        float inc = s;
        #pragma unroll
        for (int off = 1; off < 64; off <<= 1) {
            const float n = __shfl_up(inc, off, 64);
            if (lane >= off) inc += n;
        }
        if (lane == 63) wt[wid] = inc;
        __syncthreads();
        float wpre = 0.0f, btot = 0.0f;
        #pragma unroll
        for (int i = 0; i < 4; ++i) {
            const float v = wt[i];
            if (i < wid) wpre += v;
            btot += v;
        }
        const float excl = carry + wpre + (inc - s);   // exclusive prefix for this thread
        float4 ov;
        ov.x = excl + p0;
        ov.y = excl + p1;
        ov.z = excl + p2;
        ov.w = excl + p3;
        o4[i4] = ov;
        carry += btot;
        __syncthreads();   // protect wt before next round
    }
}

// ------------------------------------------------------------------ launch
extern "C" void kernel_launch(void* const* d_in, const int* in_sizes, int n_in,
                              void* d_out, int out_size, void* d_ws, size_t ws_size,
                              hipStream_t stream) {
    const float* x    = (const float*)d_in[0];
    const void*  mask = d_in[1];
    float*       out  = (float*)d_out;

    int*   flag     = (int*)d_ws;
    float* tileSums = (float*)((char*)d_ws + 256);

    detect_kernel<<<1, TPB, 0, stream>>>((const unsigned int*)mask, flag);
    p1_tile_sums<<<dim3(TILES_PER_ROW, B_ROWS), TPB, 0, stream>>>(x, mask, flag, tileSums);
    p2_scan_tiles<<<1, B_ROWS, 0, stream>>>(tileSums);
    p3_scan<<<dim3(TILES_PER_ROW, B_ROWS), TPB, 0, stream>>>(x, mask, flag, tileSums, out);
}

// Round 2
// 55.728 us; speedup vs baseline: 1.1370x; 1.1370x over previous
//
#include <hip/hip_runtime.h>

// Masked cumulative sum along dim=1.
// x: (128, 131072) fp32, mask: (128, 131072) bool (layout auto-detected per-wave:
// int32 vs byte). out = cumsum(x * mask, axis=1), fp32.
//
// Two kernels, reduce-then-scan:
//   p1 : per-tile masked sums (tile = 8192 elems, 16 tiles/row, 2048 blocks),
//        loads batch-hoisted 4-deep for MLP.
//   p3 : re-read tiles, single-barrier block scan, row offset computed inline
//        from raw tile sums (no separate p2 dispatch, no detect dispatch).

#define TPB 256
#define B_ROWS 128
#define S_LEN 131072
#define TILE 8192
#define TPR 16                    // tiles per row
#define ROUNDS 8                  // float4 rounds per block = TILE/(TPB*4)

// --------------------------------------------------------------- detection
// If mask is int32, every 32-bit word is exactly 0 or 1. If it is byte-bool,
// a word packs 4 bytes in {0,1}: P(word<=1) = 1/8. Each wave reads the first
// 256 words (1 KB, in-bounds under both layouts); all <=1 ==> int32.
__device__ __forceinline__ bool detect_mask_i32(const void* __restrict__ mask,
                                                int lane) {
    const unsigned int* m32 = (const unsigned int*)mask;
    const unsigned int a = m32[lane * 4 + 0];
    const unsigned int b = m32[lane * 4 + 1];
    const unsigned int c = m32[lane * 4 + 2];
    const unsigned int d = m32[lane * 4 + 3];
    return __all((a | b | c | d) <= 1u) != 0;
}

template <bool I32>
__device__ __forceinline__ float4 load_mask4(const void* __restrict__ mask,
                                             int i4) {
    float4 m;
    if constexpr (I32) {
        const int4 v = ((const int4*)mask)[i4];
        m.x = (float)v.x; m.y = (float)v.y; m.z = (float)v.z; m.w = (float)v.w;
    } else {
        const unsigned int w = ((const unsigned int*)mask)[i4];
        m.x = (float)(w & 0xffu);
        m.y = (float)((w >> 8) & 0xffu);
        m.z = (float)((w >> 16) & 0xffu);
        m.w = (float)((w >> 24) & 0xffu);
    }
    return m;
}

// ----------------------------------------------------------------- phase 1
template <bool I32>
__device__ __forceinline__ float tile_masked_sum(const float4* __restrict__ x4,
                                                 const void* __restrict__ mask,
                                                 int base4, int t) {
    float s = 0.0f;
    #pragma unroll
    for (int b = 0; b < 2; ++b) {
        float4 xv[4];
        #pragma unroll
        for (int j = 0; j < 4; ++j) xv[j] = x4[base4 + (b * 4 + j) * TPB + t];
        if constexpr (I32) {
            int4 mv[4];
            #pragma unroll
            for (int j = 0; j < 4; ++j)
                mv[j] = ((const int4*)mask)[base4 + (b * 4 + j) * TPB + t];
            #pragma unroll
            for (int j = 0; j < 4; ++j)
                s += xv[j].x * (float)mv[j].x + xv[j].y * (float)mv[j].y +
                     xv[j].z * (float)mv[j].z + xv[j].w * (float)mv[j].w;
        } else {
            unsigned int mw[4];
            #pragma unroll
            for (int j = 0; j < 4; ++j)
                mw[j] = ((const unsigned int*)mask)[base4 + (b * 4 + j) * TPB + t];
            #pragma unroll
            for (int j = 0; j < 4; ++j) {
                s += xv[j].x * (float)(mw[j] & 0xffu);
                s += xv[j].y * (float)((mw[j] >> 8) & 0xffu);
                s += xv[j].z * (float)((mw[j] >> 16) & 0xffu);
                s += xv[j].w * (float)((mw[j] >> 24) & 0xffu);
            }
        }
    }
    return s;
}

__global__ void __launch_bounds__(TPB)
p1_tile_sums(const float* __restrict__ x, const void* __restrict__ mask,
             float* __restrict__ tileSums) {
    const int tl = blockIdx.x;
    const int r  = blockIdx.y;
    const int t  = threadIdx.x;
    const int lane = t & 63, wid = t >> 6;
    const int base4 = (r * S_LEN + tl * TILE) >> 2;
    const float4* __restrict__ x4 = (const float4*)x;

    const bool m_i32 = detect_mask_i32(mask, lane);
    float s = m_i32 ? tile_masked_sum<true>(x4, mask, base4, t)
                    : tile_masked_sum<false>(x4, mask, base4, t);

    #pragma unroll
    for (int off = 32; off > 0; off >>= 1) s += __shfl_xor(s, off, 64);
    __shared__ float wt[4];
    if (lane == 0) wt[wid] = s;
    __syncthreads();
    if (t == 0) tileSums[r * TPR + tl] = wt[0] + wt[1] + wt[2] + wt[3];
}

// ----------------------------------------------------------------- phase 3
template <bool I32>
__device__ __forceinline__ void tile_scan(const float4* __restrict__ x4,
                                          const void* __restrict__ mask,
                                          float4* __restrict__ o4,
                                          int base4, int t, int lane, int wid,
                                          float rowoff, float (*wt)[4]) {
    float pr[ROUNDS][4];   // per-thread inclusive prefixes within the 4
    float sl[ROUNDS];      // per-thread round sums

    #pragma unroll
    for (int b = 0; b < 2; ++b) {
        float4 xv[4];
        #pragma unroll
        for (int j = 0; j < 4; ++j) xv[j] = x4[base4 + (b * 4 + j) * TPB + t];
        #pragma unroll
        for (int j = 0; j < 4; ++j) {
            const int rd = b * 4 + j;
            const float4 mv = load_mask4<I32>(mask, base4 + rd * TPB + t);
            const float v0 = xv[j].x * mv.x;
            const float v1 = xv[j].y * mv.y;
            const float v2 = xv[j].z * mv.z;
            const float v3 = xv[j].w * mv.w;
            pr[rd][0] = v0;
            pr[rd][1] = pr[rd][0] + v1;
            pr[rd][2] = pr[rd][1] + v2;
            pr[rd][3] = pr[rd][2] + v3;
            sl[rd] = pr[rd][3];
        }
    }

    // 8 wave-inclusive scans of the per-round thread sums
    float inc[ROUNDS];
    #pragma unroll
    for (int rd = 0; rd < ROUNDS; ++rd) {
        float v = sl[rd];
        #pragma unroll
        for (int off = 1; off < 64; off <<= 1) {
            const float n = __shfl_up(v, off, 64);
            if (lane >= off) v += n;
        }
        inc[rd] = v;
        if (lane == 63) wt[rd][wid] = v;
    }
    __syncthreads();

    float carry = rowoff;
    #pragma unroll
    for (int rd = 0; rd < ROUNDS; ++rd) {
        float wpre = 0.0f, btot = 0.0f;
        #pragma unroll
        for (int w = 0; w < 4; ++w) {
            const float v = wt[rd][w];
            if (w < wid) wpre += v;
            btot += v;
        }
        const float excl = carry + wpre + (inc[rd] - sl[rd]);
        float4 ov;
        ov.x = excl + pr[rd][0];
        ov.y = excl + pr[rd][1];
        ov.z = excl + pr[rd][2];
        ov.w = excl + pr[rd][3];
        o4[base4 + rd * TPB + t] = ov;
        carry += btot;
    }
}

__global__ void __launch_bounds__(TPB)
p3_scan(const float* __restrict__ x, const void* __restrict__ mask,
        const float* __restrict__ tileSums, float* __restrict__ out) {
    const int tl = blockIdx.x;
    const int r  = blockIdx.y;
    const int t  = threadIdx.x;
    const int lane = t & 63, wid = t >> 6;
    const int base4 = (r * S_LEN + tl * TILE) >> 2;
    const float4* __restrict__ x4 = (const float4*)x;
    float4* __restrict__ o4 = (float4*)out;

    const bool m_i32 = detect_mask_i32(mask, lane);

    // Row offset: exclusive prefix of this row's raw tile sums (64 B, L2-hot),
    // computed redundantly by every thread.
    const float4* ts4 = (const float4*)(tileSums + r * TPR);
    float rowoff = 0.0f;
    #pragma unroll
    for (int q = 0; q < 4; ++q) {
        const float4 v = ts4[q];
        const int i0 = q * 4;
        rowoff += (i0 + 0 < tl ? v.x : 0.0f) + (i0 + 1 < tl ? v.y : 0.0f) +
                  (i0 + 2 < tl ? v.z : 0.0f) + (i0 + 3 < tl ? v.w : 0.0f);
    }

    __shared__ float wt[ROUNDS][4];
    if (m_i32) tile_scan<true >(x4, mask, o4, base4, t, lane, wid, rowoff, wt);
    else       tile_scan<false>(x4, mask, o4, base4, t, lane, wid, rowoff, wt);
}

// ------------------------------------------------------------------ launch
extern "C" void kernel_launch(void* const* d_in, const int* in_sizes, int n_in,
                              void* d_out, int out_size, void* d_ws, size_t ws_size,
                              hipStream_t stream) {
    const float* x    = (const float*)d_in[0];
    const void*  mask = d_in[1];
    float*       out  = (float*)d_out;
    float* tileSums   = (float*)d_ws;   // 2048 floats

    p1_tile_sums<<<dim3(TPR, B_ROWS), TPB, 0, stream>>>(x, mask, tileSums);
    p3_scan<<<dim3(TPR, B_ROWS), TPB, 0, stream>>>(x, mask, tileSums, out);
}

// Round 4
// 55.061 us; speedup vs baseline: 1.1508x; 1.0121x over previous
//
#include <hip/hip_runtime.h>

// Masked cumulative sum along dim=1.
// x: (128, 131072) fp32, mask: (128, 131072) bool (byte layout in practice;
// int32 fallback auto-detected per-wave). out = cumsum(x * mask, axis=1), fp32.
//
// Two kernels, reduce-then-scan:
//   p1 : per-tile masked sums (tile = 8192 elems, 16 tiles/row, 2048 blocks).
//        Detect word + all 8 x-loads issued before the detect branch resolves;
//        byte path fully hoisted, int32 fallback register-cheap.
//   p3 : re-read tiles, single-barrier block scan, row offset computed inline
//        from raw tile sums. out written with NON-TEMPORAL stores so the
//        64 MiB output stream does not evict x+mask (80 MiB) from the 256 MiB
//        Infinity Cache between graph replays.

#define TPB 256
#define B_ROWS 128
#define S_LEN 131072
#define TILE 8192
#define TPR 16                    // tiles per row
#define ROUNDS 8                  // float4 rounds per block = TILE/(TPB*4)

typedef float f32x4 __attribute__((ext_vector_type(4)));   // clang-native, NT-store-compatible

__device__ __forceinline__ float4 unpack_mask_u32(unsigned int w) {
    float4 m;
    m.x = (float)(w & 0xffu);
    m.y = (float)((w >> 8) & 0xffu);
    m.z = (float)((w >> 16) & 0xffu);
    m.w = (float)((w >> 24) & 0xffu);
    return m;
}

// ----------------------------------------------------------------- phase 1
__global__ void __launch_bounds__(TPB)
p1_tile_sums(const float* __restrict__ x, const void* __restrict__ mask,
             float* __restrict__ tileSums) {
    const int tl = blockIdx.x;
    const int r  = blockIdx.y;
    const int t  = threadIdx.x;
    const int lane = t & 63, wid = t >> 6;
    const int base4 = (r * S_LEN + tl * TILE) >> 2;
    const float4* __restrict__ x4 = (const float4*)x;

    // Detection: 1 word per lane from the first 256 B of mask (L3-hot, same
    // for every block). Byte-bool mask packs 4 bytes in {0,1} per word:
    // P(word<=1)=1/8, so 64 words all <=1 => int32 layout (P_err = 8^-64).
    const unsigned int dw = ((const unsigned int*)mask)[lane];

    // Issue ALL x-tile loads before the detect branch resolves (the branch's
    // s_waitcnt only needs the detect word; x stays in flight).
    float4 xv[ROUNDS];
    #pragma unroll
    for (int rd = 0; rd < ROUNDS; ++rd) xv[rd] = x4[base4 + rd * TPB + t];

    const bool m_i32 = __all(dw <= 1u) != 0;

    float s = 0.0f;
    if (!m_i32) {
        // Live path: byte mask, deep-hoisted word loads.
        unsigned int mw[ROUNDS];
        #pragma unroll
        for (int rd = 0; rd < ROUNDS; ++rd)
            mw[rd] = ((const unsigned int*)mask)[base4 + rd * TPB + t];
        #pragma unroll
        for (int rd = 0; rd < ROUNDS; ++rd) {
            const float4 mv = unpack_mask_u32(mw[rd]);
            s += xv[rd].x * mv.x + xv[rd].y * mv.y +
                 xv[rd].z * mv.z + xv[rd].w * mv.w;
        }
    } else {
        // Fallback: int32 mask, register-cheap (keeps p1 VGPR low).
        for (int rd = 0; rd < ROUNDS; ++rd) {
            const int4 mv = ((const int4*)mask)[base4 + rd * TPB + t];
            s += xv[rd].x * (float)mv.x + xv[rd].y * (float)mv.y +
                 xv[rd].z * (float)mv.z + xv[rd].w * (float)mv.w;
        }
    }

    #pragma unroll
    for (int off = 32; off > 0; off >>= 1) s += __shfl_xor(s, off, 64);
    __shared__ float wt[4];
    if (lane == 0) wt[wid] = s;
    __syncthreads();
    if (t == 0) tileSums[r * TPR + tl] = wt[0] + wt[1] + wt[2] + wt[3];
}

// ----------------------------------------------------------------- phase 3
__global__ void __launch_bounds__(TPB)
p3_scan(const float* __restrict__ x, const void* __restrict__ mask,
        const float* __restrict__ tileSums, float* __restrict__ out) {
    const int tl = blockIdx.x;
    const int r  = blockIdx.y;
    const int t  = threadIdx.x;
    const int lane = t & 63, wid = t >> 6;
    const int base4 = (r * S_LEN + tl * TILE) >> 2;
    const float4* __restrict__ x4 = (const float4*)x;
    f32x4* __restrict__ o4 = (f32x4*)out;

    const unsigned int dw = ((const unsigned int*)mask)[lane];

    float4 xv[ROUNDS];
    #pragma unroll
    for (int rd = 0; rd < ROUNDS; ++rd) xv[rd] = x4[base4 + rd * TPB + t];

    // Row offset: exclusive prefix of this row's raw tile sums (64 B, L2-hot),
    // computed redundantly by every thread.
    const float4* ts4 = (const float4*)(tileSums + r * TPR);
    float rowoff = 0.0f;
    #pragma unroll
    for (int q = 0; q < 4; ++q) {
        const float4 v = ts4[q];
        const int i0 = q * 4;
        rowoff += (i0 + 0 < tl ? v.x : 0.0f) + (i0 + 1 < tl ? v.y : 0.0f) +
                  (i0 + 2 < tl ? v.z : 0.0f) + (i0 + 3 < tl ? v.w : 0.0f);
    }

    const bool m_i32 = __all(dw <= 1u) != 0;

    float pr[ROUNDS][4];   // per-thread inclusive prefixes within the 4
    float sl[ROUNDS];      // per-thread round sums

    if (!m_i32) {
        unsigned int mw[ROUNDS];
        #pragma unroll
        for (int rd = 0; rd < ROUNDS; ++rd)
            mw[rd] = ((const unsigned int*)mask)[base4 + rd * TPB + t];
        #pragma unroll
        for (int rd = 0; rd < ROUNDS; ++rd) {
            const float4 mv = unpack_mask_u32(mw[rd]);
            pr[rd][0] = xv[rd].x * mv.x;
            pr[rd][1] = pr[rd][0] + xv[rd].y * mv.y;
            pr[rd][2] = pr[rd][1] + xv[rd].z * mv.z;
            pr[rd][3] = pr[rd][2] + xv[rd].w * mv.w;
            sl[rd] = pr[rd][3];
        }
    } else {
        for (int rd = 0; rd < ROUNDS; ++rd) {
            const int4 mv = ((const int4*)mask)[base4 + rd * TPB + t];
            pr[rd][0] = xv[rd].x * (float)mv.x;
            pr[rd][1] = pr[rd][0] + xv[rd].y * (float)mv.y;
            pr[rd][2] = pr[rd][1] + xv[rd].z * (float)mv.z;
            pr[rd][3] = pr[rd][2] + xv[rd].w * (float)mv.w;
            sl[rd] = pr[rd][3];
        }
    }

    // 8 wave-inclusive scans of the per-round thread sums
    __shared__ float wt[ROUNDS][4];
    float inc[ROUNDS];
    #pragma unroll
    for (int rd = 0; rd < ROUNDS; ++rd) {
        float v = sl[rd];
        #pragma unroll
        for (int off = 1; off < 64; off <<= 1) {
            const float n = __shfl_up(v, off, 64);
            if (lane >= off) v += n;
        }
        inc[rd] = v;
        if (lane == 63) wt[rd][wid] = v;
    }
    __syncthreads();

    float carry = rowoff;
    #pragma unroll
    for (int rd = 0; rd < ROUNDS; ++rd) {
        float wpre = 0.0f, btot = 0.0f;
        #pragma unroll
        for (int w = 0; w < 4; ++w) {
            const float v = wt[rd][w];
            if (w < wid) wpre += v;
            btot += v;
        }
        const float excl = carry + wpre + (inc[rd] - sl[rd]);
        f32x4 ov;
        ov.x = excl + pr[rd][0];
        ov.y = excl + pr[rd][1];
        ov.z = excl + pr[rd][2];
        ov.w = excl + pr[rd][3];
        // Non-temporal: keep the 64 MiB output stream out of the Infinity
        // Cache so x+mask stay L3-resident across replays.
        __builtin_nontemporal_store(ov, &o4[base4 + rd * TPB + t]);
        carry += btot;
    }
}

// ------------------------------------------------------------------ launch
extern "C" void kernel_launch(void* const* d_in, const int* in_sizes, int n_in,
                              void* d_out, int out_size, void* d_ws, size_t ws_size,
                              hipStream_t stream) {
    const float* x    = (const float*)d_in[0];
    const void*  mask = d_in[1];
    float*       out  = (float*)d_out;
    float* tileSums   = (float*)d_ws;   // 2048 floats

    p1_tile_sums<<<dim3(TPR, B_ROWS), TPB, 0, stream>>>(x, mask, tileSums);
    p3_scan<<<dim3(TPR, B_ROWS), TPB, 0, stream>>>(x, mask, tileSums, out);
}